// Round 1
// baseline (116.797 us; speedup 1.0000x reference)
//
#include <hip/hip_runtime.h>
#include <hip/hip_fp16.h>
#include <math.h>

#define BATCH 16384
#define MAXF 32
#define NFEAT 768
#define FT_OUT 1024
#define CHUNK 32                      // columns per chunk; 1 B/col -> 32-B LDS row
#define NCHUNK (FT_OUT / CHUNK)       // 32 chunks
#define GROUPS 32                     // 1024 blocks = 4/CU, exactly 4 iters each
#define CH_BYTES (NFEAT * CHUNK)      // 24576 B = 24 KiB

// compile-time component select for unrolled loops (f is a constant after unroll)
#define GET4(a, f) (((f) & 3) == 0 ? (a)[(f) >> 2].x : \
                    ((f) & 3) == 1 ? (a)[(f) >> 2].y : \
                    ((f) & 3) == 2 ? (a)[(f) >> 2].z : (a)[(f) >> 2].w)

typedef unsigned int uint_t;

// ---- e5m2 (bf8) helpers -------------------------------------------------
// e5m2 is f16 truncated to its top byte: f16 = byte << 8 EXACTLY (same
// exponent field, 2 mantissa bits). Encode: RNE-round the f16 low byte away.
__device__ __forceinline__ uint_t rne_e5m2(float w) {
    unsigned short h = __half_as_ushort(__float2half(w));   // f32->f16 RNE
    unsigned short t = (unsigned short)(h + 0x7F + ((h >> 8) & 1)); // RNE to byte
    return (uint_t)(t >> 8) & 0xFFu;
}
__device__ __forceinline__ uint_t pack4_e5m2(float4 f) {
    return rne_e5m2(f.x) | (rne_e5m2(f.y) << 8) |
           (rne_e5m2(f.z) << 16) | (rne_e5m2(f.w) << 24);
}
// Decode 4 bf8 (one dword) -> two half2, fused with the accumulate.
// v_perm_b32 builds [b1,0,b0,0] / [b3,0,b2,0]: each f16 = byte<<8.
// q passed as BOTH perm operands so the src0/src1 byte-numbering convention
// is irrelevant (sel uses only 0x00-0x03 byte picks and 0x0C = const 0).
__device__ __forceinline__ void fma4_bf8(uint_t q, __half2 v2,
                                         __half2& a0, __half2& a1) {
    uint_t lo = __builtin_amdgcn_perm(q, q, 0x010C000Cu); // halves: b0<<8, b1<<8
    uint_t hi = __builtin_amdgcn_perm(q, q, 0x030C020Cu); // halves: b2<<8, b3<<8
    a0 = __hfma2(*reinterpret_cast<__half2*>(&lo), v2, a0);
    a1 = __hfma2(*reinterpret_cast<__half2*>(&hi), v2, a1);
}

// Main: stage fp32 chunk -> e5m2 LDS (24 KiB), stream samples, write per-chunk
// partial logits with PLAIN STORES (each (chunk,sample) written exactly once).
//
// Hard-won invariants kept from R1-R13:
//  - static __shared__ only (dynamic LDS breaks reg promotion; R7/R11)
//  - NO __threadfence (evicts L2-resident table; R8 vs R9)
//  - plain stores, no atomics/memset
//  - no L2-side gather assist (rate-bound; R6/R13)
// New this round (R14): e5m2 table halves both LDS bytes AND ds_read_b128
// count (16 cols/lane instead of 8). Wall model: dur ~= #b128 x eff_cyc;
// 2.10M -> 1.05M instrs at eff ~13-14 => predict ~22-27 us (was 47.7).
// Decode = 1 v_perm per 2 cols; added VALU stays under the LDS wall
// (~10.6k vs ~13.3k cyc per iter-round per SIMD/CU).
// 24 KiB LDS -> 4 blocks/CU (16 waves); GROUPS=32 -> uniform 4 iters/block.
__global__ __launch_bounds__(256, 4) void nnboard_main(
    const float* __restrict__ values,
    const int*   __restrict__ stm_idx,
    const int*   __restrict__ nstm_idx,
    const float* __restrict__ ft_w,
    const float* __restrict__ ft_b,
    const float* __restrict__ out_w,
    float*       __restrict__ partials)   // [NCHUNK][BATCH]
{
    __shared__ __align__(16) unsigned char s_tab[CH_BYTES]; // 24 KiB, 32-B rows

    const int tid = threadIdx.x;
    const int c = blockIdx.x % NCHUNK;    // chunk: cols [32c, 32c+32)
    const int g = blockIdx.x / NCHUNK;    // stripe 0..31
    const __half2 zero2 = __float2half2_rn(0.f);

    // ---- stage chunk c from fp32 ft_w as e5m2: 8 lanes/row, 128-B coalesced
    {
        const int lane8 = tid & 7;
        const int rbase = tid >> 3;
        #pragma unroll
        for (int k = 0; k < NFEAT / 32; ++k) {
            const int r = k * 32 + rbase;
            const float4 f = *(const float4*)(ft_w + (size_t)r * FT_OUT + c * CHUNK + lane8 * 4);
            *(uint_t*)(s_tab + r * CHUNK + lane8 * 4) = pack4_e5m2(f);
        }
    }
    __syncthreads();

    const int grp = tid >> 1;             // 0..127 : sample slot per iteration
    const int j   = tid & 1;              // lane within sample (owns 16 cols)
    const int col0 = c * CHUNK + j * 16;
    const unsigned char* my_tab = s_tab + j * 16; // + row*CHUNK per gathered row

    float4 bia[4], ws[4], wn[4];
    #pragma unroll
    for (int k = 0; k < 4; ++k) {
        bia[k] = *(const float4*)(ft_b + col0 + 4 * k);
        ws[k]  = *(const float4*)(out_w + col0 + 4 * k);
        wn[k]  = *(const float4*)(out_w + FT_OUT + col0 + 4 * k);
    }

    for (int it = g; it < BATCH / 128; it += GROUPS) {   // exactly 4 iters
        const int b = it * 128 + grp;

        const int4*   sp = (const int4*)(stm_idx + b * MAXF);
        const int4*   np = (const int4*)(nstm_idx + b * MAXF);
        const float4* vp = (const float4*)(values + b * MAXF);
        int4 si[8], ni[8];
        float4 vv[8];
        #pragma unroll
        for (int k = 0; k < 8; ++k) { si[k] = sp[k]; ni[k] = np[k]; vv[k] = vp[k]; }

        __half2 accs[8] = {zero2, zero2, zero2, zero2, zero2, zero2, zero2, zero2};
        __half2 accn[8] = {zero2, zero2, zero2, zero2, zero2, zero2, zero2, zero2};

        #pragma unroll
        for (int f = 0; f < MAXF; ++f) {
            const int is = GET4(si, f);
            const int in = GET4(ni, f);
            const __half2 v2 = __float2half2_rn(GET4(vv, f));
            const uint4 qs = *(const uint4*)(my_tab + is * CHUNK);
            const uint4 qn = *(const uint4*)(my_tab + in * CHUNK);
            fma4_bf8(qs.x, v2, accs[0], accs[1]);
            fma4_bf8(qs.y, v2, accs[2], accs[3]);
            fma4_bf8(qs.z, v2, accs[4], accs[5]);
            fma4_bf8(qs.w, v2, accs[6], accs[7]);
            fma4_bf8(qn.x, v2, accn[0], accn[1]);
            fma4_bf8(qn.y, v2, accn[2], accn[3]);
            fma4_bf8(qn.z, v2, accn[4], accn[5]);
            fma4_bf8(qn.w, v2, accn[6], accn[7]);
        }

        float p = 0.f;
        {
            auto clip = [](float x) { return fminf(fmaxf(x, 0.f), 1.f); };
            #pragma unroll
            for (int k = 0; k < 4; ++k) {
                const float2 s0 = __half22float2(accs[2 * k]);
                const float2 s1 = __half22float2(accs[2 * k + 1]);
                const float2 n0 = __half22float2(accn[2 * k]);
                const float2 n1 = __half22float2(accn[2 * k + 1]);
                p = fmaf(clip(s0.x + bia[k].x), ws[k].x, p);
                p = fmaf(clip(s0.y + bia[k].y), ws[k].y, p);
                p = fmaf(clip(s1.x + bia[k].z), ws[k].z, p);
                p = fmaf(clip(s1.y + bia[k].w), ws[k].w, p);
                p = fmaf(clip(n0.x + bia[k].x), wn[k].x, p);
                p = fmaf(clip(n0.y + bia[k].y), wn[k].y, p);
                p = fmaf(clip(n1.x + bia[k].z), wn[k].z, p);
                p = fmaf(clip(n1.y + bia[k].w), wn[k].w, p);
            }
        }

        // reduce 2 lanes of the sample pair (tid = grp*2 + j, contiguous)
        p += __shfl_down(p, 1, 64);
        if (j == 0) partials[c * BATCH + b] = p;   // plain store, 32 lanes/wave
    }
}

// Epilogue: sum 32 chunk-partials per sample (coalesced: stride-BATCH rows,
// consecutive samples -> consecutive addresses), + out_b, sigmoid.
__global__ __launch_bounds__(256) void reduce_sigmoid_kernel(
    const float* __restrict__ partials,
    const float* __restrict__ out_b,
    float* __restrict__ out)
{
    const int i = blockIdx.x * 256 + threadIdx.x;
    float s = out_b[0];
    #pragma unroll
    for (int k = 0; k < NCHUNK; ++k)
        s += partials[k * BATCH + i];
    out[i] = 1.f / (1.f + expf(-s));
}

extern "C" void kernel_launch(void* const* d_in, const int* in_sizes, int n_in,
                              void* d_out, int out_size, void* d_ws, size_t ws_size,
                              hipStream_t stream) {
    const float* values   = (const float*)d_in[0];
    const int*   stm_idx  = (const int*)d_in[1];
    const int*   nstm_idx = (const int*)d_in[2];
    const float* ft_w     = (const float*)d_in[3];
    const float* ft_b     = (const float*)d_in[4];
    const float* out_w    = (const float*)d_in[5];
    const float* out_b    = (const float*)d_in[6];
    float*       out      = (float*)d_out;

    float* partials = (float*)d_ws;   // [32][16384] f32 = 2 MB, fully overwritten

    nnboard_main<<<NCHUNK * GROUPS, 256, 0, stream>>>(
        values, stm_idx, nstm_idx, ft_w, ft_b, out_w, partials);
    reduce_sigmoid_kernel<<<BATCH / 256, 256, 0, stream>>>(partials, out_b, out);
}

// Round 2
// 116.604 us; speedup vs baseline: 1.0016x; 1.0016x over previous
//
#include <hip/hip_runtime.h>
#include <hip/hip_fp16.h>
#include <math.h>

#define BATCH 16384
#define MAXF 32
#define NFEAT 768
#define FT_OUT 1024
#define CHUNK 32                      // columns per chunk; 1 B/col -> 32-B LDS row
#define NCHUNK (FT_OUT / CHUNK)       // 32 chunks
#define GROUPS 32                     // 1024 blocks = 4/CU, exactly 4 iters each
#define CH_BYTES (NFEAT * CHUNK)      // 24576 B = 24 KiB

typedef unsigned int uint_t;

// ---- e5m2 (bf8) helpers -------------------------------------------------
// e5m2 is f16 truncated to its top byte: f16 = byte << 8 EXACTLY. Encode:
// RNE-round the f16 low byte away. (Verified R14: absmax identical to f16.)
__device__ __forceinline__ uint_t rne_e5m2(float w) {
    unsigned short h = __half_as_ushort(__float2half(w));   // f32->f16 RNE
    unsigned short t = (unsigned short)(h + 0x7F + ((h >> 8) & 1)); // RNE to byte
    return (uint_t)(t >> 8) & 0xFFu;
}
__device__ __forceinline__ uint_t pack4_e5m2(float4 f) {
    return rne_e5m2(f.x) | (rne_e5m2(f.y) << 8) |
           (rne_e5m2(f.z) << 16) | (rne_e5m2(f.w) << 24);
}
// Decode 4 bf8 (one dword) -> two half2, fused with the accumulate.
// 1 v_perm per 2 cols; q passed as both perm srcs so byte-numbering
// convention is irrelevant (sel uses 0x00-0x03 picks + 0x0C = const 0).
__device__ __forceinline__ void fma4_bf8(uint_t q, __half2 v2,
                                         __half2& a0, __half2& a1) {
    uint_t lo = __builtin_amdgcn_perm(q, q, 0x010C000Cu); // b0<<8, b1<<8
    uint_t hi = __builtin_amdgcn_perm(q, q, 0x030C020Cu); // b2<<8, b3<<8
    a0 = __hfma2(*reinterpret_cast<__half2*>(&lo), v2, a0);
    a1 = __hfma2(*reinterpret_cast<__half2*>(&hi), v2, a1);
}

// Hard-won invariants kept from R1-R13:
//  - static __shared__ only (dynamic LDS breaks reg promotion; R7/R11)
//  - NO __threadfence (evicts L2-resident table; R8 vs R9)
//  - plain stores, no atomics/memset
//  - no L2-side gather assist (rate-bound; R6/R13)
// R14 lesson: e5m2 halved LDS instrs (2.10M->1.05M) as predicted but VALU
// busy-cycles rose 72% -- live set (~106 regs: 24 sample-cache + 48 f32
// consts + 16 accs) vs the 64-VGPR squeeze => remat/shuffle bloat.
// R15: same e5m2 structure, pressure fixed:
//  - sample data rotated one int4/int4/float4 triple at a time (static
//    component access preserved -> no scratch)
//  - epilogue constants reloaded per outer iteration behind an asm
//    "memory" hoist-blocker (4 iters total, L1-resident -> free)
// Wall model: LDS pipe ~4.1k instr/CU x ~18 cyc = ~75k cyc => ~32us main.
__global__ __launch_bounds__(256, 4) void nnboard_main(
    const float* __restrict__ values,
    const int*   __restrict__ stm_idx,
    const int*   __restrict__ nstm_idx,
    const float* __restrict__ ft_w,
    const float* __restrict__ ft_b,
    const float* __restrict__ out_w,
    float*       __restrict__ partials)   // [NCHUNK][BATCH]
{
    __shared__ __align__(16) unsigned char s_tab[CH_BYTES]; // 24 KiB, 32-B rows

    const int tid = threadIdx.x;
    const int c = blockIdx.x % NCHUNK;    // chunk: cols [32c, 32c+32)
    const int g = blockIdx.x / NCHUNK;    // stripe 0..31
    const __half2 zero2 = __float2half2_rn(0.f);

    // ---- stage chunk c from fp32 ft_w as e5m2: 8 lanes/row, 128-B coalesced
    {
        const int lane8 = tid & 7;
        const int rbase = tid >> 3;
        #pragma unroll
        for (int k = 0; k < NFEAT / 32; ++k) {
            const int r = k * 32 + rbase;
            const float4 f = *(const float4*)(ft_w + (size_t)r * FT_OUT + c * CHUNK + lane8 * 4);
            *(uint_t*)(s_tab + r * CHUNK + lane8 * 4) = pack4_e5m2(f);
        }
    }
    __syncthreads();

    const int grp = tid >> 1;             // 0..127 : sample slot per iteration
    const int j   = tid & 1;              // lane within sample (owns 16 cols)
    const int col0 = c * CHUNK + j * 16;
    const unsigned char* my_tab = s_tab + j * 16; // + row*CHUNK per gathered row

    for (int it = g; it < BATCH / 128; it += GROUPS) {   // exactly 4 iters
        const int b = it * 128 + grp;

        const int4*   sp = (const int4*)(stm_idx + b * MAXF);
        const int4*   np = (const int4*)(nstm_idx + b * MAXF);
        const float4* vp = (const float4*)(values + b * MAXF);

        __half2 accs[8] = {zero2, zero2, zero2, zero2, zero2, zero2, zero2, zero2};
        __half2 accn[8] = {zero2, zero2, zero2, zero2, zero2, zero2, zero2, zero2};

        // one sample-data triple live at a time (+1 prefetched), components
        // accessed statically inside the unrolled body (no scratch).
        int4   s4 = sp[0], n4 = np[0];
        float4 v4 = vp[0];

        #define FEAT(CS, CN, CV) { \
            const __half2 v2 = __float2half2_rn(CV); \
            const uint4 qs = *(const uint4*)(my_tab + CS * CHUNK); \
            const uint4 qn = *(const uint4*)(my_tab + CN * CHUNK); \
            fma4_bf8(qs.x, v2, accs[0], accs[1]); \
            fma4_bf8(qs.y, v2, accs[2], accs[3]); \
            fma4_bf8(qs.z, v2, accs[4], accs[5]); \
            fma4_bf8(qs.w, v2, accs[6], accs[7]); \
            fma4_bf8(qn.x, v2, accn[0], accn[1]); \
            fma4_bf8(qn.y, v2, accn[2], accn[3]); \
            fma4_bf8(qn.z, v2, accn[4], accn[5]); \
            fma4_bf8(qn.w, v2, accn[6], accn[7]); }

        #pragma unroll
        for (int k = 0; k < 8; ++k) {
            int4 s4n, n4n; float4 v4n;
            if (k < 7) { s4n = sp[k + 1]; n4n = np[k + 1]; v4n = vp[k + 1]; }
            FEAT(s4.x, n4.x, v4.x);
            FEAT(s4.y, n4.y, v4.y);
            FEAT(s4.z, n4.z, v4.z);
            FEAT(s4.w, n4.w, v4.w);
            if (k < 7) { s4 = s4n; n4 = n4n; v4 = v4n; }
        }
        #undef FEAT

        // Block hoisting of the epilogue constant loads out of the it-loop:
        // keeps bia/ws/wn live only inside the epilogue (L1-resident, 4x).
        asm volatile("" ::: "memory");

        float p = 0.f;
        {
            auto clip = [](float x) { return fminf(fmaxf(x, 0.f), 1.f); };
            #pragma unroll
            for (int k = 0; k < 4; ++k) {
                const float4 bia = *(const float4*)(ft_b + col0 + 4 * k);
                const float4 ws  = *(const float4*)(out_w + col0 + 4 * k);
                const float4 wn  = *(const float4*)(out_w + FT_OUT + col0 + 4 * k);
                const float2 s0 = __half22float2(accs[2 * k]);
                const float2 s1 = __half22float2(accs[2 * k + 1]);
                const float2 n0 = __half22float2(accn[2 * k]);
                const float2 n1 = __half22float2(accn[2 * k + 1]);
                p = fmaf(clip(s0.x + bia.x), ws.x, p);
                p = fmaf(clip(s0.y + bia.y), ws.y, p);
                p = fmaf(clip(s1.x + bia.z), ws.z, p);
                p = fmaf(clip(s1.y + bia.w), ws.w, p);
                p = fmaf(clip(n0.x + bia.x), wn.x, p);
                p = fmaf(clip(n0.y + bia.y), wn.y, p);
                p = fmaf(clip(n1.x + bia.z), wn.z, p);
                p = fmaf(clip(n1.y + bia.w), wn.w, p);
            }
        }

        // reduce 2 lanes of the sample pair (tid = grp*2 + j, contiguous)
        p += __shfl_down(p, 1, 64);
        if (j == 0) partials[c * BATCH + b] = p;   // plain store, 32 lanes/wave
    }
}

// Epilogue: sum 32 chunk-partials per sample (coalesced: stride-BATCH rows,
// consecutive samples -> consecutive addresses), + out_b, sigmoid.
__global__ __launch_bounds__(256) void reduce_sigmoid_kernel(
    const float* __restrict__ partials,
    const float* __restrict__ out_b,
    float* __restrict__ out)
{
    const int i = blockIdx.x * 256 + threadIdx.x;
    float s = out_b[0];
    #pragma unroll
    for (int k = 0; k < NCHUNK; ++k)
        s += partials[k * BATCH + i];
    out[i] = 1.f / (1.f + expf(-s));
}

extern "C" void kernel_launch(void* const* d_in, const int* in_sizes, int n_in,
                              void* d_out, int out_size, void* d_ws, size_t ws_size,
                              hipStream_t stream) {
    const float* values   = (const float*)d_in[0];
    const int*   stm_idx  = (const int*)d_in[1];
    const int*   nstm_idx = (const int*)d_in[2];
    const float* ft_w     = (const float*)d_in[3];
    const float* ft_b     = (const float*)d_in[4];
    const float* out_w    = (const float*)d_in[5];
    const float* out_b    = (const float*)d_in[6];
    float*       out      = (float*)d_out;

    float* partials = (float*)d_ws;   // [32][16384] f32 = 2 MB, fully overwritten

    nnboard_main<<<NCHUNK * GROUPS, 256, 0, stream>>>(
        values, stm_idx, nstm_idx, ft_w, ft_b, out_w, partials);
    reduce_sigmoid_kernel<<<BATCH / 256, 256, 0, stream>>>(partials, out_b, out);
}